// Round 1
// baseline (395.845 us; speedup 1.0000x reference)
//
#include <hip/hip_runtime.h>
#include <hip/hip_bf16.h>

typedef __attribute__((ext_vector_type(8))) short bf16x8;
typedef __attribute__((ext_vector_type(4))) float f32x4;

#define NB 32
#define NI 256
#define NO 256
#define HH 28
#define WW 28
#define PH 30
#define PW 30

// h[b][j] = sigmoid(x_gap[b,:16] . w1[j,:16] + b1[j]),  j in [0,512)
__global__ void h_kernel(const float* __restrict__ xg, const float* __restrict__ w1,
                         const float* __restrict__ b1, float* __restrict__ h) {
    int b = blockIdx.x;
    int j = threadIdx.x;
    const float* g = xg + b * 16;
    const float* w = w1 + j * 16;
    float s = b1[j];
#pragma unroll
    for (int c = 0; c < 16; ++c) s += g[c] * w[c];
    h[b * 512 + j] = 1.0f / (1.0f + expf(-s));
}

// Wr[o][kh][kw][i] = bf16(w2[o*2304 + i*9 + kh*3 + kw])
__global__ void wr_kernel(const float* __restrict__ w2, __hip_bfloat16* __restrict__ wr) {
    int idx = blockIdx.x * 256 + threadIdx.x;
    int i = idx & 255;
    int t = idx >> 8;
    int kw = t % 3; t /= 3;
    int kh = t % 3;
    int o = t / 3;
    wr[idx] = __float2bfloat16(w2[o * 2304 + i * 9 + kh * 3 + kw]);
}

// xp[b][p'][q'][i] = bf16(x[b][i][p'-1][q'-1]) for interior, borders pre-zeroed by memset.
// One block: (b, p, i-chunk of 64). LDS transpose for coalesced read+write.
__global__ void xpose_kernel(const float* __restrict__ x, __hip_bfloat16* __restrict__ xp) {
    __shared__ float tile[64][29];
    int blk = blockIdx.x;
    int icnk = blk & 3;
    int t = blk >> 2;
    int p = t % 28;
    int b = t / 28;
    int i0 = icnk * 64;
    for (int e = threadIdx.x; e < 64 * 28; e += 256) {
        int ii = e / 28, q = e % 28;
        tile[ii][q] = x[((b * 256 + i0 + ii) * 28 + p) * 28 + q];
    }
    __syncthreads();
    for (int e = threadIdx.x; e < 28 * 64; e += 256) {
        int q = e >> 6, ii = e & 63;
        xp[((b * 30 + p + 1) * 30 + q + 1) * 256 + i0 + ii] = __float2bfloat16(tile[ii][q]);
    }
}

// Implicit-GEMM conv. Block = (ntile 0..6, otile 0..3, b 0..31), 256 thr = 4 waves.
// Wave w: o-range otile*64 + w*16 .. +15, n-range = 112 spatial positions (4 rows x 28).
// K loop: 9 taps x 8 i-chunks of 32; acc[0] for i<128, acc[1] for i>=128.
__global__ __launch_bounds__(256) void conv_kernel(
    const __hip_bfloat16* __restrict__ xp, const __hip_bfloat16* __restrict__ wr,
    const float* __restrict__ h, float* __restrict__ out) {
    const int ntile = blockIdx.x;
    const int otile = blockIdx.y;
    const int b = blockIdx.z;
    const int lane = threadIdx.x & 63;
    const int wv = threadIdx.x >> 6;
    const int kcol = lane & 15;   // A-row (o) for loads, D-col (n) for stores
    const int klo = lane >> 4;    // k-subchunk 0..3

    const short* wbase = (const short*)(wr) + (otile * 64 + wv * 16 + kcol) * 2304 + klo * 8;
    const short* xbase = (const short*)(xp) + b * (PH * PW * NI) + klo * 8;

    int np[7], nq[7];
    const short* xb[7];
#pragma unroll
    for (int f = 0; f < 7; ++f) {
        int n = f * 16 + kcol;
        int po = ntile * 4 + n / 28;
        int qo = n % 28;
        np[f] = po;
        nq[f] = qo;
        xb[f] = xbase + (po * PW + qo) * NI;
    }

    f32x4 acc[2][7];
#pragma unroll
    for (int s = 0; s < 2; ++s)
#pragma unroll
        for (int f = 0; f < 7; ++f) acc[s][f] = (f32x4){0.f, 0.f, 0.f, 0.f};

    for (int khw = 0; khw < 9; ++khw) {
        const short* wp = wbase + khw * 256;
        const int xoff = ((khw / 3) * PW + (khw % 3)) * NI;
#pragma unroll
        for (int icc = 0; icc < 8; ++icc) {
            bf16x8 a = *(const bf16x8*)(wp + icc * 32);
            f32x4* ac = acc[icc >> 2];
#pragma unroll
            for (int f = 0; f < 7; ++f) {
                bf16x8 bv = *(const bf16x8*)(xb[f] + xoff + icc * 32);
                ac[f] = __builtin_amdgcn_mfma_f32_16x16x32_bf16(a, bv, ac[f], 0, 0, 0);
            }
        }
    }

    // epilogue: y = h[b,2o]*acc0 + h[b,2o+1]*acc1
    const int obase = otile * 64 + wv * 16 + klo * 4;
#pragma unroll
    for (int r = 0; r < 4; ++r) {
        int o = obase + r;
        float h0 = h[b * 512 + 2 * o];
        float h1 = h[b * 512 + 2 * o + 1];
        float* ob = out + ((size_t)(b * NO + o)) * HH * WW;
#pragma unroll
        for (int f = 0; f < 7; ++f) {
            ob[np[f] * WW + nq[f]] = h0 * acc[0][f][r] + h1 * acc[1][f][r];
        }
    }
}

extern "C" void kernel_launch(void* const* d_in, const int* in_sizes, int n_in,
                              void* d_out, int out_size, void* d_ws, size_t ws_size,
                              hipStream_t stream) {
    const float* x  = (const float*)d_in[0];
    const float* xg = (const float*)d_in[1];
    const float* w1 = (const float*)d_in[2];
    const float* b1 = (const float*)d_in[3];
    const float* w2 = (const float*)d_in[4];
    float* out = (float*)d_out;

    char* ws = (char*)d_ws;
    float* h = (float*)ws;                                          // 64 KB
    __hip_bfloat16* wr = (__hip_bfloat16*)(ws + 65536);             // 1.18 MB
    __hip_bfloat16* xp = (__hip_bfloat16*)(ws + 65536 + 1179648);   // 14.75 MB

    hipMemsetAsync(xp, 0, (size_t)NB * PH * PW * NI * 2, stream);
    h_kernel<<<NB, 512, 0, stream>>>(xg, w1, b1, h);
    wr_kernel<<<2304, 256, 0, stream>>>(w2, wr);
    xpose_kernel<<<NB * 28 * 4, 256, 0, stream>>>(x, xp);
    conv_kernel<<<dim3(7, 4, NB), 256, 0, stream>>>(xp, wr, h, out);
}

// Round 2
// 105.803 us; speedup vs baseline: 3.7413x; 3.7413x over previous
//
#include <hip/hip_runtime.h>
#include <hip/hip_bf16.h>

typedef __attribute__((ext_vector_type(8))) short bf16x8;
typedef __attribute__((ext_vector_type(4))) float f32x4;

#define NB 32
#define NI 256
#define NO 256
#define HH 28
#define WW 28
#define PH 30
#define PW 30
#define XS_BYTES (6 * 30 * 256 * 2)   // 92160 B x-slab per block

// h[b][j] = sigmoid(x_gap[b,:16] . w1[j,:16] + b1[j]),  j in [0,512)
__global__ void h_kernel(const float* __restrict__ xg, const float* __restrict__ w1,
                         const float* __restrict__ b1, float* __restrict__ h) {
    int b = blockIdx.x;
    int j = threadIdx.x;
    const float* g = xg + b * 16;
    const float* w = w1 + j * 16;
    float s = b1[j];
#pragma unroll
    for (int c = 0; c < 16; ++c) s += g[c] * w[c];
    h[b * 512 + j] = 1.0f / (1.0f + expf(-s));
}

// Wr[o][kh][kw][i] = bf16(w2[o*2304 + i*9 + kh*3 + kw])
__global__ void wr_kernel(const float* __restrict__ w2, __hip_bfloat16* __restrict__ wr) {
    int idx = blockIdx.x * 256 + threadIdx.x;
    int i = idx & 255;
    int t = idx >> 8;
    int kw = t % 3; t /= 3;
    int kh = t % 3;
    int o = t / 3;
    wr[idx] = __float2bfloat16(w2[o * 2304 + i * 9 + kh * 3 + kw]);
}

// xp[b][p'][q'][i] = bf16(x[b][i][p'-1][q'-1]) interior; borders pre-zeroed by memset.
__global__ void xpose_kernel(const float* __restrict__ x, __hip_bfloat16* __restrict__ xp) {
    __shared__ float tile[64][29];
    int blk = blockIdx.x;
    int icnk = blk & 3;
    int t = blk >> 2;
    int p = t % 28;
    int b = t / 28;
    int i0 = icnk * 64;
    for (int e = threadIdx.x; e < 64 * 28; e += 256) {
        int ii = e / 28, q = e % 28;
        tile[ii][q] = x[((b * 256 + i0 + ii) * 28 + p) * 28 + q];
    }
    __syncthreads();
    for (int e = threadIdx.x; e < 28 * 64; e += 256) {
        int q = e >> 6, ii = e & 63;
        xp[((b * 30 + p + 1) * 30 + q + 1) * 256 + i0 + ii] = __float2bfloat16(tile[ii][q]);
    }
}

// Implicit-GEMM conv, LDS-resident x-slab, zero barriers in the K-loop.
// Grid (7 n-tiles, 32 b), 512 thr = 8 waves: wave = (mw = w&3)*64 o-range,
// (nw = w>>2) picks n-frags {0..3} or {4..6}. K = 9 taps x 8 chunks of 32 ch.
__global__ __launch_bounds__(512, 2) void conv_kernel(
    const __hip_bfloat16* __restrict__ xp, const __hip_bfloat16* __restrict__ wr,
    const float* __restrict__ h, float* __restrict__ out) {
    __shared__ __align__(16) char Xs[XS_BYTES];
    const int nt = blockIdx.x;
    const int b = blockIdx.y;
    const int tid = threadIdx.x;
    const int lane = tid & 63;
    const int wv = tid >> 6;
    const int mw = wv & 3;
    const int nw = wv >> 2;
    const int kcol = lane & 15;
    const int klo = lane >> 4;

    // ---- stage Xs: linear (coalesced) global read, swizzled LDS write.
    // LDS[d ^ ((pos&7)<<4)] = src[d]; involution -> read logical L at L^((L>>9&7)<<4).
    {
        const char* src = (const char*)(xp + ((size_t)b * 900 + nt * 120) * 256);
        for (int c = tid; c < XS_BYTES / 16; c += 512) {
            unsigned d = (unsigned)c * 16u;
            unsigned sd = d ^ (((d >> 9) & 7u) << 4);
            *(bf16x8*)(Xs + sd) = *(const bf16x8*)(src + d);
        }
    }
    __syncthreads();

    // B-frag lane geometry (frag fi -> output position n = f*16 + kcol)
    const int f0 = (nw == 0) ? 0 : 4;
    unsigned bbase[4];  // swizzled LDS byte base (per tap add pos-offset, per icc XOR icc<<6)
    int posb[4], nidx[4];
#pragma unroll
    for (int fi = 0; fi < 4; ++fi) {
        int f = f0 + fi;
        if (f > 6) f = 6;  // nw=1, fi=3: dup of frag 6 (acc discarded)
        int n = f * 16 + kcol;
        int r = n / 28;
        int q = n - r * 28;
        posb[fi] = r * 30 + q;
        nidx[fi] = n;
    }

    // A pointers: lane kcol = o-row within frag, klo = 8-ch subchunk
    const short* wbase[4];
#pragma unroll
    for (int mf = 0; mf < 4; ++mf)
        wbase[mf] = (const short*)wr + (size_t)(mw * 64 + mf * 16 + kcol) * 2304 + klo * 8;

    f32x4 acc[2][4][4];
#pragma unroll
    for (int hs = 0; hs < 2; ++hs)
#pragma unroll
        for (int mf = 0; mf < 4; ++mf)
#pragma unroll
            for (int fi = 0; fi < 4; ++fi) acc[hs][mf][fi] = (f32x4){0.f, 0.f, 0.f, 0.f};

    bf16x8 a0 = *(const bf16x8*)(wbase[0]);
    bf16x8 a1 = *(const bf16x8*)(wbase[1]);
    bf16x8 a2 = *(const bf16x8*)(wbase[2]);
    bf16x8 a3 = *(const bf16x8*)(wbase[3]);

    for (int tap = 0; tap < 9; ++tap) {
        const int kh = (tap * 11) >> 5;          // tap/3
        const int tapoff = 27 * kh + tap;        // kh*30 + kw
        // per-tap swizzled B bases (bits 6..8 of unswizzled base are 0 -> inner XOR ok)
        unsigned bb[4];
#pragma unroll
        for (int fi = 0; fi < 4; ++fi) {
            int pos = posb[fi] + tapoff;
            unsigned base = (unsigned)(pos * 512 + klo * 16);
            bb[fi] = base ^ (((unsigned)pos & 7u) << 4);
        }
        const short* wt0 = wbase[0] + tap * 256;
        const short* wt1 = wbase[1] + tap * 256;
        const short* wt2 = wbase[2] + tap * 256;
        const short* wt3 = wbase[3] + tap * 256;
#pragma unroll
        for (int icc = 0; icc < 8; ++icc) {
            // prefetch next step's A frags (last one overruns into scratch; discarded)
            bf16x8 n0 = *(const bf16x8*)(wt0 + (icc + 1) * 32);
            bf16x8 n1 = *(const bf16x8*)(wt1 + (icc + 1) * 32);
            bf16x8 n2 = *(const bf16x8*)(wt2 + (icc + 1) * 32);
            bf16x8 n3 = *(const bf16x8*)(wt3 + (icc + 1) * 32);

            bf16x8 bv0 = *(const bf16x8*)(Xs + (bbase[0] = bb[0] ^ (unsigned)(icc << 6)));
            bf16x8 bv1 = *(const bf16x8*)(Xs + (bb[1] ^ (unsigned)(icc << 6)));
            bf16x8 bv2 = *(const bf16x8*)(Xs + (bb[2] ^ (unsigned)(icc << 6)));
            bf16x8 bv3;
            if (nw == 0) {
                bv3 = *(const bf16x8*)(Xs + (bb[3] ^ (unsigned)(icc << 6)));
            } else {
                bv3 = bv2;  // dup; acc[.][.][3] never stored for nw=1
            }
            constexpr int HS = 0;  // placeholder; real sel below via icc
            const int hs = (icc >> 2);  // compile-time within unroll
            if (icc < 4) {
                acc[0][0][0] = __builtin_amdgcn_mfma_f32_16x16x32_bf16(a0, bv0, acc[0][0][0], 0, 0, 0);
                acc[0][0][1] = __builtin_amdgcn_mfma_f32_16x16x32_bf16(a0, bv1, acc[0][0][1], 0, 0, 0);
                acc[0][0][2] = __builtin_amdgcn_mfma_f32_16x16x32_bf16(a0, bv2, acc[0][0][2], 0, 0, 0);
                acc[0][0][3] = __builtin_amdgcn_mfma_f32_16x16x32_bf16(a0, bv3, acc[0][0][3], 0, 0, 0);
                acc[0][1][0] = __builtin_amdgcn_mfma_f32_16x16x32_bf16(a1, bv0, acc[0][1][0], 0, 0, 0);
                acc[0][1][1] = __builtin_amdgcn_mfma_f32_16x16x32_bf16(a1, bv1, acc[0][1][1], 0, 0, 0);
                acc[0][1][2] = __builtin_amdgcn_mfma_f32_16x16x32_bf16(a1, bv2, acc[0][1][2], 0, 0, 0);
                acc[0][1][3] = __builtin_amdgcn_mfma_f32_16x16x32_bf16(a1, bv3, acc[0][1][3], 0, 0, 0);
                acc[0][2][0] = __builtin_amdgcn_mfma_f32_16x16x32_bf16(a2, bv0, acc[0][2][0], 0, 0, 0);
                acc[0][2][1] = __builtin_amdgcn_mfma_f32_16x16x32_bf16(a2, bv1, acc[0][2][1], 0, 0, 0);
                acc[0][2][2] = __builtin_amdgcn_mfma_f32_16x16x32_bf16(a2, bv2, acc[0][2][2], 0, 0, 0);
                acc[0][2][3] = __builtin_amdgcn_mfma_f32_16x16x32_bf16(a2, bv3, acc[0][2][3], 0, 0, 0);
                acc[0][3][0] = __builtin_amdgcn_mfma_f32_16x16x32_bf16(a3, bv0, acc[0][3][0], 0, 0, 0);
                acc[0][3][1] = __builtin_amdgcn_mfma_f32_16x16x32_bf16(a3, bv1, acc[0][3][1], 0, 0, 0);
                acc[0][3][2] = __builtin_amdgcn_mfma_f32_16x16x32_bf16(a3, bv2, acc[0][3][2], 0, 0, 0);
                acc[0][3][3] = __builtin_amdgcn_mfma_f32_16x16x32_bf16(a3, bv3, acc[0][3][3], 0, 0, 0);
            } else {
                acc[1][0][0] = __builtin_amdgcn_mfma_f32_16x16x32_bf16(a0, bv0, acc[1][0][0], 0, 0, 0);
                acc[1][0][1] = __builtin_amdgcn_mfma_f32_16x16x32_bf16(a0, bv1, acc[1][0][1], 0, 0, 0);
                acc[1][0][2] = __builtin_amdgcn_mfma_f32_16x16x32_bf16(a0, bv2, acc[1][0][2], 0, 0, 0);
                acc[1][0][3] = __builtin_amdgcn_mfma_f32_16x16x32_bf16(a0, bv3, acc[1][0][3], 0, 0, 0);
                acc[1][1][0] = __builtin_amdgcn_mfma_f32_16x16x32_bf16(a1, bv0, acc[1][1][0], 0, 0, 0);
                acc[1][1][1] = __builtin_amdgcn_mfma_f32_16x16x32_bf16(a1, bv1, acc[1][1][1], 0, 0, 0);
                acc[1][1][2] = __builtin_amdgcn_mfma_f32_16x16x32_bf16(a1, bv2, acc[1][1][2], 0, 0, 0);
                acc[1][1][3] = __builtin_amdgcn_mfma_f32_16x16x32_bf16(a1, bv3, acc[1][1][3], 0, 0, 0);
                acc[1][2][0] = __builtin_amdgcn_mfma_f32_16x16x32_bf16(a2, bv0, acc[1][2][0], 0, 0, 0);
                acc[1][2][1] = __builtin_amdgcn_mfma_f32_16x16x32_bf16(a2, bv1, acc[1][2][1], 0, 0, 0);
                acc[1][2][2] = __builtin_amdgcn_mfma_f32_16x16x32_bf16(a2, bv2, acc[1][2][2], 0, 0, 0);
                acc[1][2][3] = __builtin_amdgcn_mfma_f32_16x16x32_bf16(a2, bv3, acc[1][2][3], 0, 0, 0);
                acc[1][3][0] = __builtin_amdgcn_mfma_f32_16x16x32_bf16(a3, bv0, acc[1][3][0], 0, 0, 0);
                acc[1][3][1] = __builtin_amdgcn_mfma_f32_16x16x32_bf16(a3, bv1, acc[1][3][1], 0, 0, 0);
                acc[1][3][2] = __builtin_amdgcn_mfma_f32_16x16x32_bf16(a3, bv2, acc[1][3][2], 0, 0, 0);
                acc[1][3][3] = __builtin_amdgcn_mfma_f32_16x16x32_bf16(a3, bv3, acc[1][3][3], 0, 0, 0);
            }
            (void)hs; (void)HS;
            a0 = n0; a1 = n1; a2 = n2; a3 = n3;
        }
    }

    // epilogue: y = h[b,2o]*acc0 + h[b,2o+1]*acc1
    const int obase0 = mw * 64 + klo * 4;
#pragma unroll
    for (int mf = 0; mf < 4; ++mf) {
#pragma unroll
        for (int r = 0; r < 4; ++r) {
            int o = obase0 + mf * 16 + r;
            float h0 = h[b * 512 + 2 * o];
            float h1 = h[b * 512 + 2 * o + 1];
            float* ob = out + ((size_t)(b * NO + o)) * 784 + nt * 112;
#pragma unroll
            for (int fi = 0; fi < 4; ++fi) {
                if (nw == 0 || fi < 3) {
                    ob[nidx[fi]] = h0 * acc[0][mf][fi][r] + h1 * acc[1][mf][fi][r];
                }
            }
        }
    }
}

extern "C" void kernel_launch(void* const* d_in, const int* in_sizes, int n_in,
                              void* d_out, int out_size, void* d_ws, size_t ws_size,
                              hipStream_t stream) {
    const float* x = (const float*)d_in[0];
    const float* xg = (const float*)d_in[1];
    const float* w1 = (const float*)d_in[2];
    const float* b1 = (const float*)d_in[3];
    const float* w2 = (const float*)d_in[4];
    float* out = (float*)d_out;

    char* ws = (char*)d_ws;
    float* h = (float*)ws;                                         // 64 KB
    __hip_bfloat16* wr = (__hip_bfloat16*)(ws + 65536);            // 1.18 MB
    __hip_bfloat16* xp = (__hip_bfloat16*)(ws + 65536 + 1179648);  // 14.75 MB

    hipMemsetAsync(xp, 0, (size_t)NB * PH * PW * NI * 2, stream);
    h_kernel<<<NB, 512, 0, stream>>>(xg, w1, b1, h);
    wr_kernel<<<2304, 256, 0, stream>>>(w2, wr);
    xpose_kernel<<<NB * 28 * 4, 256, 0, stream>>>(x, xp);
    conv_kernel<<<dim3(7, NB), 512, 0, stream>>>(xp, wr, h, out);
}

// Round 3
// 65.159 us; speedup vs baseline: 6.0751x; 1.6238x over previous
//
#include <hip/hip_runtime.h>
#include <hip/hip_bf16.h>

typedef __attribute__((ext_vector_type(8))) short bf16x8;
typedef __attribute__((ext_vector_type(4))) float f32x4;

#define NB 32
#define NI 256
#define NO 256
#define PH 30
#define PW 30
#define XS_BYTES (6 * 30 * 256 * 2)   // 92160 B x-slab per block

// Wr[o][kh][kw][i] = bf16(w2[o*2304 + i*9 + kh*3 + kw])
__global__ void wr_kernel(const float* __restrict__ w2, __hip_bfloat16* __restrict__ wr) {
    int idx = blockIdx.x * 256 + threadIdx.x;
    int i = idx & 255;
    int t = idx >> 8;
    int kw = t % 3; t /= 3;
    int kh = t % 3;
    int o = t / 3;
    wr[idx] = __float2bfloat16(w2[o * 2304 + i * 9 + kh * 3 + kw]);
}

// xp[b][pr][q][i] = bf16(x[b][i][pr-1][q-1]) interior; borders written as zero here.
// grid: b(32) x pr(30) x icnk(4)
__global__ void xpose_kernel(const float* __restrict__ x, __hip_bfloat16* __restrict__ xp) {
    __shared__ float tile[64][29];
    int blk = blockIdx.x;
    int icnk = blk & 3;
    int t = blk >> 2;
    int pr = t % 30;
    int b = t / 30;
    int i0 = icnk * 64;
    __hip_bfloat16* dst = xp + ((size_t)(b * 30 + pr) * 30) * 256 + i0;
    const bf16x8 z = (bf16x8){0, 0, 0, 0, 0, 0, 0, 0};
    if (pr == 0 || pr == 29) {
        for (int e = threadIdx.x; e < 30 * 8; e += 256) {
            int q = e >> 3, part = e & 7;
            *(bf16x8*)((short*)(dst + (size_t)q * 256) + part * 8) = z;
        }
        return;
    }
    int p = pr - 1;
    for (int e = threadIdx.x; e < 64 * 28; e += 256) {
        int ii = e / 28, q = e % 28;
        tile[ii][q] = x[((b * 256 + i0 + ii) * 28 + p) * 28 + q];
    }
    __syncthreads();
    for (int e = threadIdx.x; e < 28 * 64; e += 256) {
        int q = e >> 6, ii = e & 63;
        dst[(size_t)(q + 1) * 256 + ii] = __float2bfloat16(tile[ii][q]);
    }
    if (threadIdx.x < 16) {
        int col = (threadIdx.x >> 3) * 29, part = threadIdx.x & 7;
        *(bf16x8*)((short*)(dst + (size_t)col * 256) + part * 8) = z;
    }
}

// Implicit-GEMM conv. 224 blocks (XCD-swizzled), 512 thr = 8 waves.
// Wave w: o-range [w*32, w*32+31] (2 m-frags), all 112 n (7 n-frags).
// K-loop: 9 taps x 8 chunks of 32ch, zero barriers, depth-1 A prefetch (even/odd ring).
__global__ __launch_bounds__(512, 2) void conv_kernel(
    const __hip_bfloat16* __restrict__ xp, const __hip_bfloat16* __restrict__ wr,
    const float* __restrict__ xg, const float* __restrict__ w1,
    const float* __restrict__ b1, float* __restrict__ out) {
    __shared__ __align__(16) char Xs[XS_BYTES];
    __shared__ float hsm[512];
    const int bid = blockIdx.x;
    const int v = (bid & 7) * 28 + (bid >> 3);   // bijective: 224 % 8 == 0
    const int b = v / 7;
    const int nt = v - b * 7;
    const int tid = threadIdx.x;
    const int lane = tid & 63;
    const int wv = tid >> 6;
    const int kcol = lane & 15;
    const int klo = lane >> 4;

    // h[j] = sigmoid(xg[b].w1[j] + b1[j]), one j per thread
    {
        float s = b1[tid];
        const float* g = xg + b * 16;
        const float* w = w1 + tid * 16;
#pragma unroll
        for (int c = 0; c < 16; ++c) s += g[c] * w[c];
        hsm[tid] = 1.0f / (1.0f + expf(-s));
    }

    // stage x-slab: linear global read, swizzled LDS write (involution in bits 4-6)
    {
        const char* src = (const char*)(xp + ((size_t)b * 900 + nt * 120) * 256);
        for (int c = tid; c < XS_BYTES / 16; c += 512) {
            unsigned d = (unsigned)c * 16u;
            unsigned sd = d ^ (((d >> 9) & 7u) << 4);
            *(bf16x8*)(Xs + sd) = *(const bf16x8*)(src + d);
        }
    }
    __syncthreads();

    int posb[7];
#pragma unroll
    for (int nf = 0; nf < 7; ++nf) {
        int n = nf * 16 + kcol;
        int r = n / 28;
        int q = n - r * 28;
        posb[nf] = r * 30 + q;
    }

    const short* wb0 = (const short*)wr + (size_t)(wv * 32 + kcol) * 2304 + klo * 8;
    const short* wb1 = wb0 + 16 * 2304;

    f32x4 acc[2][2][7];
#pragma unroll
    for (int hs = 0; hs < 2; ++hs)
#pragma unroll
        for (int mf = 0; mf < 2; ++mf)
#pragma unroll
            for (int nf = 0; nf < 7; ++nf) acc[hs][mf][nf] = (f32x4){0.f, 0.f, 0.f, 0.f};

    bf16x8 aA0 = *(const bf16x8*)(wb0);
    bf16x8 aA1 = *(const bf16x8*)(wb1);
    bf16x8 aB0, aB1;
    const short* pa0 = wb0 + 32;
    const short* pa1 = wb1 + 32;

    for (int tap = 0; tap < 9; ++tap) {
        const int kh = (tap * 11) >> 5;        // tap/3
        const int tapoff = 27 * kh + tap;      // kh*30 + kw
        unsigned bb[7];
#pragma unroll
        for (int nf = 0; nf < 7; ++nf) {
            int pos = posb[nf] + tapoff;
            unsigned base = (unsigned)(pos * 512 + klo * 16);
            bb[nf] = base ^ (((unsigned)pos & 7u) << 4);
        }
#pragma unroll
        for (int icp = 0; icp < 4; ++icp) {
            const int hs = icp >> 1;
            {   // even step: consume aA, prefetch aB
                const unsigned x6 = (unsigned)(icp * 2) << 6;
                aB0 = *(const bf16x8*)pa0; pa0 += 32;
                aB1 = *(const bf16x8*)pa1; pa1 += 32;
#pragma unroll
                for (int nf = 0; nf < 7; ++nf) {
                    bf16x8 bv = *(const bf16x8*)(Xs + (bb[nf] ^ x6));
                    acc[hs][0][nf] = __builtin_amdgcn_mfma_f32_16x16x32_bf16(aA0, bv, acc[hs][0][nf], 0, 0, 0);
                    acc[hs][1][nf] = __builtin_amdgcn_mfma_f32_16x16x32_bf16(aA1, bv, acc[hs][1][nf], 0, 0, 0);
                }
            }
            {   // odd step: consume aB, prefetch aA
                const unsigned x6 = (unsigned)(icp * 2 + 1) << 6;
                aA0 = *(const bf16x8*)pa0; pa0 += 32;
                aA1 = *(const bf16x8*)pa1; pa1 += 32;
#pragma unroll
                for (int nf = 0; nf < 7; ++nf) {
                    bf16x8 bv = *(const bf16x8*)(Xs + (bb[nf] ^ x6));
                    acc[hs][0][nf] = __builtin_amdgcn_mfma_f32_16x16x32_bf16(aB0, bv, acc[hs][0][nf], 0, 0, 0);
                    acc[hs][1][nf] = __builtin_amdgcn_mfma_f32_16x16x32_bf16(aB1, bv, acc[hs][1][nf], 0, 0, 0);
                }
            }
        }
    }

    // epilogue: y = h[2o]*acc0 + h[2o+1]*acc1
#pragma unroll
    for (int mf = 0; mf < 2; ++mf) {
#pragma unroll
        for (int r = 0; r < 4; ++r) {
            int o = wv * 32 + mf * 16 + klo * 4 + r;
            float h0 = hsm[2 * o];
            float h1 = hsm[2 * o + 1];
            float* ob = out + ((size_t)b * NO + o) * 784 + nt * 112;
#pragma unroll
            for (int nf = 0; nf < 7; ++nf) {
                ob[nf * 16 + kcol] = h0 * acc[0][mf][nf][r] + h1 * acc[1][mf][nf][r];
            }
        }
    }
}

extern "C" void kernel_launch(void* const* d_in, const int* in_sizes, int n_in,
                              void* d_out, int out_size, void* d_ws, size_t ws_size,
                              hipStream_t stream) {
    const float* x = (const float*)d_in[0];
    const float* xg = (const float*)d_in[1];
    const float* w1 = (const float*)d_in[2];
    const float* b1 = (const float*)d_in[3];
    const float* w2 = (const float*)d_in[4];
    float* out = (float*)d_out;

    char* ws = (char*)d_ws;
    __hip_bfloat16* wr = (__hip_bfloat16*)ws;                 // 1,179,648 B
    __hip_bfloat16* xp = (__hip_bfloat16*)(ws + 1179648);     // 14,745,600 B

    wr_kernel<<<2304, 256, 0, stream>>>(w2, wr);
    xpose_kernel<<<NB * 30 * 4, 256, 0, stream>>>(x, xp);
    conv_kernel<<<224, 512, 0, stream>>>(xp, wr, xg, w1, b1, out);
}

// Round 5
// 64.390 us; speedup vs baseline: 6.1476x; 1.0119x over previous
//
#include <hip/hip_runtime.h>
#include <hip/hip_bf16.h>

typedef __attribute__((ext_vector_type(8))) short bf16x8;
typedef __attribute__((ext_vector_type(4))) float f32x4;

#define NB 32
#define NO 256
#define XS_BYTES (6 * 30 * 512)   // 92160 B x-slab (6 rows x 30 cols x 256ch bf16)

// Wr[o][kh][kw][i] = bf16(w2[o*2304 + i*9 + kh*3 + kw])
__global__ void wr_kernel(const float* __restrict__ w2, __hip_bfloat16* __restrict__ wr) {
    int idx = blockIdx.x * 256 + threadIdx.x;
    int i = idx & 255;
    int t = idx >> 8;
    int kw = t % 3; t /= 3;
    int kh = t % 3;
    int o = t / 3;
    wr[idx] = __float2bfloat16(w2[o * 2304 + i * 9 + kh * 3 + kw]);
}

// xp[b][pr][q][i] = bf16(x[b][i][pr-1][q-1]) interior; borders written as zero here.
__global__ void xpose_kernel(const float* __restrict__ x, __hip_bfloat16* __restrict__ xp) {
    __shared__ float tile[64][29];
    int blk = blockIdx.x;
    int icnk = blk & 3;
    int t = blk >> 2;
    int pr = t % 30;
    int b = t / 30;
    int i0 = icnk * 64;
    __hip_bfloat16* dst = xp + ((size_t)(b * 30 + pr) * 30) * 256 + i0;
    const bf16x8 z = (bf16x8){0, 0, 0, 0, 0, 0, 0, 0};
    if (pr == 0 || pr == 29) {
        for (int e = threadIdx.x; e < 30 * 8; e += 256) {
            int q = e >> 3, part = e & 7;
            *(bf16x8*)((short*)(dst + (size_t)q * 256) + part * 8) = z;
        }
        return;
    }
    int p = pr - 1;
    for (int e = threadIdx.x; e < 64 * 28; e += 256) {
        int ii = e / 28, q = e % 28;
        tile[ii][q] = x[((b * 256 + i0 + ii) * 28 + p) * 28 + q];
    }
    __syncthreads();
    for (int e = threadIdx.x; e < 28 * 64; e += 256) {
        int q = e >> 6, ii = e & 63;
        dst[(size_t)(q + 1) * 256 + ii] = __float2bfloat16(tile[ii][q]);
    }
    if (threadIdx.x < 16) {
        int col = (threadIdx.x >> 3) * 29, part = threadIdx.x & 7;
        *(bf16x8*)((short*)(dst + (size_t)col * 256) + part * 8) = z;
    }
}

#define MFMA4(nf_, bv_)                                                                   \
    acc[0][nf_] = __builtin_amdgcn_mfma_f32_16x16x32_bf16(a0, bv_, acc[0][nf_], 0, 0, 0); \
    acc[1][nf_] = __builtin_amdgcn_mfma_f32_16x16x32_bf16(a1, bv_, acc[1][nf_], 0, 0, 0); \
    acc[2][nf_] = __builtin_amdgcn_mfma_f32_16x16x32_bf16(a2, bv_, acc[2][nf_], 0, 0, 0); \
    acc[3][nf_] = __builtin_amdgcn_mfma_f32_16x16x32_bf16(a3, bv_, acc[3][nf_], 0, 0, 0);

// Implicit-GEMM conv. 224 blocks (XCD-swizzled), 512 thr = 8 waves = 4 mw x 2 kw2.
// Wave (mw,kw2): o-range [mw*64, +63] (4 m-frags), all 112 n (7 n-frags),
// channel half kw2 (128 ch = 4 chunks of 32). Single acc set per wave (h-group == kw2).
// LDS slab swizzle key = (q + 4r)&7: increments by 1 per output position even across
// row wraps (4*30 == 0 mod 8) -> conflict-free ds_read_b128 for every tap/chunk.
__global__ __launch_bounds__(512, 2) void conv_kernel(
    const __hip_bfloat16* __restrict__ xp, const __hip_bfloat16* __restrict__ wr,
    const float* __restrict__ xg, const float* __restrict__ w1,
    const float* __restrict__ b1, float* __restrict__ out) {
    __shared__ __align__(16) char Xs[XS_BYTES];
    __shared__ float hsm[512];
    const int bid = blockIdx.x;
    const int v = (bid & 7) * 28 + (bid >> 3);   // bijective XCD swizzle (224 % 8 == 0)
    const int b = v / 7;
    const int nt = v - b * 7;
    const int tid = threadIdx.x;
    const int lane = tid & 63;
    const int wv = tid >> 6;
    const int mw = wv & 3;
    const int kw2 = wv >> 2;
    const int kcol = lane & 15;
    const int klo = lane >> 4;

    // h[j] = sigmoid(xg[b].w1[j] + b1[j])
    {
        float s = b1[tid];
        const float* g = xg + b * 16;
        const float* w = w1 + tid * 16;
#pragma unroll
        for (int c = 0; c < 16; ++c) s += g[c] * w[c];
        hsm[tid] = 1.0f / (1.0f + expf(-s));
    }

    // stage slab: linear coalesced global read; store 16B chunk w of position sp at
    // sp*512 + ((w ^ key(sp))<<4), key(sp) = (q + 4r)&7.
    {
        const char* src = (const char*)(xp + ((size_t)b * 900 + nt * 120) * 256);
        for (int c = tid; c < 5760; c += 512) {
            int sp = c >> 5, w = c & 31;
            int rr = sp / 30;
            int qq = sp - rr * 30;
            int key = (qq + 4 * rr) & 7;
            *(bf16x8*)(Xs + sp * 512 + ((w ^ key) << 4)) = *(const bf16x8*)(src + (size_t)c * 16);
        }
    }
    __syncthreads();

    int sp0[7], key0[7];
#pragma unroll
    for (int nf = 0; nf < 7; ++nf) {
        int n = nf * 16 + kcol;
        int r0 = n / 28;
        int q0 = n - r0 * 28;
        sp0[nf] = r0 * 30 + q0;
        key0[nf] = q0 + 4 * r0;
    }

    // A base: wave's o-rows, its channel half. off(tap,ic) = tap*256 + ic*32 shorts.
    const short* pA0 = (const short*)wr + (size_t)(mw * 64 + 0 * 16 + kcol) * 2304 + kw2 * 128 + klo * 8;
    const short* pA1 = pA0 + 16 * 2304;
    const short* pA2 = pA0 + 32 * 2304;
    const short* pA3 = pA0 + 48 * 2304;

    f32x4 acc[4][7];
#pragma unroll
    for (int mf = 0; mf < 4; ++mf)
#pragma unroll
        for (int nf = 0; nf < 7; ++nf) acc[mf][nf] = (f32x4){0.f, 0.f, 0.f, 0.f};

    bf16x8 a0 = *(const bf16x8*)pA0;
    bf16x8 a1 = *(const bf16x8*)pA1;
    bf16x8 a2 = *(const bf16x8*)pA2;
    bf16x8 a3 = *(const bf16x8*)pA3;
    pA0 += 32; pA1 += 32; pA2 += 32; pA3 += 32;

    for (int tap = 0; tap < 9; ++tap) {
        const int kh = (tap * 11) >> 5;     // tap/3
        const int kwk = tap - kh * 3;
        unsigned tb[7];
#pragma unroll
        for (int nf = 0; nf < 7; ++nf) {
            int spv = sp0[nf] + kh * 30 + kwk;
            int key = (key0[nf] + kwk + 4 * kh) & 7;
            tb[nf] = (unsigned)(spv * 512) + (unsigned)(((klo ^ (key & 3)) << 4) | ((key >> 2) << 6));
        }
#pragma unroll
        for (int ic = 0; ic < 4; ++ic) {
            const unsigned xo = (unsigned)((kw2 * 4 + ic) << 6);
            bf16x8 bv0 = *(const bf16x8*)(Xs + (tb[0] ^ xo));
            bf16x8 bv1 = *(const bf16x8*)(Xs + (tb[1] ^ xo));
            bf16x8 bv2 = *(const bf16x8*)(Xs + (tb[2] ^ xo));
            bf16x8 bv3 = *(const bf16x8*)(Xs + (tb[3] ^ xo));
            bf16x8 bv4 = *(const bf16x8*)(Xs + (tb[4] ^ xo));
            bf16x8 bv5 = *(const bf16x8*)(Xs + (tb[5] ^ xo));
            bf16x8 bv6 = *(const bf16x8*)(Xs + (tb[6] ^ xo));
            // A prefetch for next step. Prefetch at step k is consumed at k+1, so the
            // pointer advance must be off(k+2)-off(k+1): the +160 tap-boundary jump
            // applies when ic==2 (next prefetch crosses the tap), NOT ic==3.
            bf16x8 n0 = *(const bf16x8*)pA0;
            bf16x8 n1 = *(const bf16x8*)pA1;
            bf16x8 n2 = *(const bf16x8*)pA2;
            bf16x8 n3 = *(const bf16x8*)pA3;
            const int adv = (ic == 2) ? 160 : 32;
            pA0 += adv; pA1 += adv; pA2 += adv; pA3 += adv;

            MFMA4(0, bv0)
            MFMA4(1, bv1)
            MFMA4(2, bv2)
            MFMA4(3, bv3)
            MFMA4(4, bv4)
            MFMA4(5, bv5)
            MFMA4(6, bv6)
            a0 = n0; a1 = n1; a2 = n2; a3 = n3;
        }
    }

    // ---- epilogue: combine k-halves through LDS (slab is dead), 2 rounds of 2 m-frags.
    __syncthreads();
    float* Xf = (float*)Xs;
#pragma unroll
    for (int r2 = 0; r2 < 2; ++r2) {
        if (kw2 == 1) {
#pragma unroll
            for (int mfi = 0; mfi < 2; ++mfi) {
                const int mf = r2 * 2 + mfi;
#pragma unroll
                for (int nf = 0; nf < 7; ++nf) {
#pragma unroll
                    for (int rr = 0; rr < 4; ++rr) {
                        int o = mw * 64 + mf * 16 + klo * 4 + rr;
                        int idx = (((mw * 2 + mfi) * 7 + nf) * 4 + rr) * 64 + lane;
                        Xf[idx] = hsm[2 * o + 1] * acc[mf][nf][rr];
                    }
                }
            }
        }
        __syncthreads();
        if (kw2 == 0) {
#pragma unroll
            for (int mfi = 0; mfi < 2; ++mfi) {
                const int mf = r2 * 2 + mfi;
#pragma unroll
                for (int nf = 0; nf < 7; ++nf) {
#pragma unroll
                    for (int rr = 0; rr < 4; ++rr) {
                        int o = mw * 64 + mf * 16 + klo * 4 + rr;
                        int idx = (((mw * 2 + mfi) * 7 + nf) * 4 + rr) * 64 + lane;
                        float y = hsm[2 * o] * acc[mf][nf][rr] + Xf[idx];
                        out[((size_t)b * NO + o) * 784 + nt * 112 + nf * 16 + kcol] = y;
                    }
                }
            }
        }
        __syncthreads();
    }
}

extern "C" void kernel_launch(void* const* d_in, const int* in_sizes, int n_in,
                              void* d_out, int out_size, void* d_ws, size_t ws_size,
                              hipStream_t stream) {
    const float* x = (const float*)d_in[0];
    const float* xg = (const float*)d_in[1];
    const float* w1 = (const float*)d_in[2];
    const float* b1 = (const float*)d_in[3];
    const float* w2 = (const float*)d_in[4];
    float* out = (float*)d_out;

    char* ws = (char*)d_ws;
    __hip_bfloat16* wr = (__hip_bfloat16*)ws;                 // 1,179,648 B
    __hip_bfloat16* xp = (__hip_bfloat16*)(ws + 1179648);     // 14,745,600 B

    wr_kernel<<<2304, 256, 0, stream>>>(w2, wr);
    xpose_kernel<<<NB * 30 * 4, 256, 0, stream>>>(x, xp);
    conv_kernel<<<224, 512, 0, stream>>>(xp, wr, xg, w1, b1, out);
}

// Round 6
// 53.574 us; speedup vs baseline: 7.3887x; 1.2019x over previous
//
#include <hip/hip_runtime.h>
#include <hip/hip_bf16.h>

typedef __attribute__((ext_vector_type(8))) short bf16x8;
typedef __attribute__((ext_vector_type(4))) float f32x4;

#define NB 32
#define NO 256
#define XS_BYTES (6 * 30 * 512)   // 92160 B x-slab (6 rows x 30 cols x 256ch bf16)

// wrT blocked layout: [kw2][tap][ic][mw][mf][kcol][klo][e8]
// -> per (wave,step) the 4 A-fragments are one contiguous 4096 B block;
//    flat step index s = tap*4+ic advances the block by a constant 16384 B.
__global__ void wrt_kernel(const float* __restrict__ w2, __hip_bfloat16* __restrict__ wrt) {
    int idx = blockIdx.x * 256 + threadIdx.x;   // [0, 73728) groups of 8
    int klo = idx & 3;
    int t1 = idx >> 2;
    int kcol = t1 & 15;
    int t2 = t1 >> 4;
    int mf = t2 & 3;
    int t3 = t2 >> 2;
    int mw = t3 & 3;
    int t4 = t3 >> 2;
    int ic = t4 & 3;
    int t5 = t4 >> 2;           // kw2*9 + tap
    int tap = t5 % 9;
    int kw2 = t5 / 9;
    int o = mw * 64 + mf * 16 + kcol;
    int ch = kw2 * 128 + ic * 32 + klo * 8;
    const float* s = w2 + (size_t)o * 2304 + (size_t)ch * 9 + tap;
    union { bf16x8 v; __hip_bfloat16 e[8]; } u;
#pragma unroll
    for (int e = 0; e < 8; ++e) u.e[e] = __float2bfloat16(s[e * 9]);
    *(bf16x8*)((short*)wrt + (size_t)idx * 8) = u.v;
}

// xp[b][pr][q][i] = bf16(x[b][i][pr-1][q-1]) interior; borders written as zero here.
__global__ void xpose_kernel(const float* __restrict__ x, __hip_bfloat16* __restrict__ xp) {
    __shared__ float tile[64][29];
    int blk = blockIdx.x;
    int icnk = blk & 3;
    int t = blk >> 2;
    int pr = t % 30;
    int b = t / 30;
    int i0 = icnk * 64;
    __hip_bfloat16* dst = xp + ((size_t)(b * 30 + pr) * 30) * 256 + i0;
    const bf16x8 z = (bf16x8){0, 0, 0, 0, 0, 0, 0, 0};
    if (pr == 0 || pr == 29) {
        for (int e = threadIdx.x; e < 30 * 8; e += 256) {
            int q = e >> 3, part = e & 7;
            *(bf16x8*)((short*)(dst + (size_t)q * 256) + part * 8) = z;
        }
        return;
    }
    int p = pr - 1;
    for (int e = threadIdx.x; e < 64 * 28; e += 256) {
        int ii = e / 28, q = e % 28;
        tile[ii][q] = x[((b * 256 + i0 + ii) * 28 + p) * 28 + q];
    }
    __syncthreads();
    for (int e = threadIdx.x; e < 28 * 64; e += 256) {
        int q = e >> 6, ii = e & 63;
        dst[(size_t)(q + 1) * 256 + ii] = __float2bfloat16(tile[ii][q]);
    }
    if (threadIdx.x < 16) {
        int col = (threadIdx.x >> 3) * 29, part = threadIdx.x & 7;
        *(bf16x8*)((short*)(dst + (size_t)col * 256) + part * 8) = z;
    }
}

#define MFMA4(nf_, bv_)                                                                   \
    acc[0][nf_] = __builtin_amdgcn_mfma_f32_16x16x32_bf16(a0, bv_, acc[0][nf_], 0, 0, 0); \
    acc[1][nf_] = __builtin_amdgcn_mfma_f32_16x16x32_bf16(a1, bv_, acc[1][nf_], 0, 0, 0); \
    acc[2][nf_] = __builtin_amdgcn_mfma_f32_16x16x32_bf16(a2, bv_, acc[2][nf_], 0, 0, 0); \
    acc[3][nf_] = __builtin_amdgcn_mfma_f32_16x16x32_bf16(a3, bv_, acc[3][nf_], 0, 0, 0);

// One K-step: prefetch A(step+2) into (p0..p3) from pA, compute 28 MFMAs on (a0..a3),
// then rotate. Prefetch->consume gap = 2 steps (~2x28 MFMA issues) covers L2 latency.
#define STEP(aset0, aset1, aset2, aset3, icv)                                             \
    {                                                                                     \
        bf16x8 p0 = *(const bf16x8*)(pA);                                                 \
        bf16x8 p1 = *(const bf16x8*)(pA + 512);                                           \
        bf16x8 p2 = *(const bf16x8*)(pA + 1024);                                          \
        bf16x8 p3 = *(const bf16x8*)(pA + 1536);                                          \
        pA += 8192;                                                                       \
        const unsigned xo = (unsigned)((kw2 * 4 + (icv)) << 6);                           \
        bf16x8 bv0 = *(const bf16x8*)(Xs + (tb[0] ^ xo));                                 \
        bf16x8 bv1 = *(const bf16x8*)(Xs + (tb[1] ^ xo));                                 \
        bf16x8 bv2 = *(const bf16x8*)(Xs + (tb[2] ^ xo));                                 \
        bf16x8 bv3 = *(const bf16x8*)(Xs + (tb[3] ^ xo));                                 \
        bf16x8 bv4 = *(const bf16x8*)(Xs + (tb[4] ^ xo));                                 \
        bf16x8 bv5 = *(const bf16x8*)(Xs + (tb[5] ^ xo));                                 \
        bf16x8 bv6 = *(const bf16x8*)(Xs + (tb[6] ^ xo));                                 \
        bf16x8 a0 = aset0, a1 = aset1, a2 = aset2, a3 = aset3;                            \
        MFMA4(0, bv0)                                                                     \
        MFMA4(1, bv1)                                                                     \
        MFMA4(2, bv2)                                                                     \
        MFMA4(3, bv3)                                                                     \
        MFMA4(4, bv4)                                                                     \
        MFMA4(5, bv5)                                                                     \
        MFMA4(6, bv6)                                                                     \
        aset0 = p0; aset1 = p1; aset2 = p2; aset3 = p3;                                   \
    }

// Implicit-GEMM conv. 224 blocks (XCD-swizzled), 512 thr = 8 waves = 4 mw x 2 kw2.
// Wave (mw,kw2): 64 o (4 m-frags) x 112 n (7 n-frags) x its 128-ch half.
// LDS slab swizzle key = (q+4r)&7 (conflict-free; 4*30 == 0 mod 8).
__global__ __launch_bounds__(512, 2) void conv_kernel(
    const __hip_bfloat16* __restrict__ xp, const __hip_bfloat16* __restrict__ wrt,
    const float* __restrict__ xg, const float* __restrict__ w1,
    const float* __restrict__ b1, float* __restrict__ out) {
    __shared__ __align__(16) char Xs[XS_BYTES];
    __shared__ float hsm[512];
    const int bid = blockIdx.x;
    const int v = (bid & 7) * 28 + (bid >> 3);   // bijective XCD swizzle (224 % 8 == 0)
    const int b = v / 7;
    const int nt = v - b * 7;
    const int tid = threadIdx.x;
    const int lane = tid & 63;
    const int wv = tid >> 6;
    const int mw = wv & 3;
    const int kw2 = wv >> 2;
    const int kcol = lane & 15;
    const int klo = lane >> 4;

    // h[j] = sigmoid(xg[b].w1[j] + b1[j])
    {
        float s = b1[tid];
        const float* g = xg + b * 16;
        const float* w = w1 + tid * 16;
#pragma unroll
        for (int c = 0; c < 16; ++c) s += g[c] * w[c];
        hsm[tid] = 1.0f / (1.0f + expf(-s));
    }

    // stage slab: linear coalesced global read; 16B chunk w of position sp stored at
    // sp*512 + ((w ^ key(sp))<<4), key(sp) = (q + 4r)&7.
    {
        const char* src = (const char*)(xp + ((size_t)b * 900 + nt * 120) * 256);
        for (int c = tid; c < 5760; c += 512) {
            int sp = c >> 5, w = c & 31;
            int rr = sp / 30;
            int qq = sp - rr * 30;
            int key = (qq + 4 * rr) & 7;
            *(bf16x8*)(Xs + sp * 512 + ((w ^ key) << 4)) = *(const bf16x8*)(src + (size_t)c * 16);
        }
    }
    __syncthreads();

    int sp0[7], key0[7];
#pragma unroll
    for (int nf = 0; nf < 7; ++nf) {
        int n = nf * 16 + kcol;
        int r0 = n / 28;
        int q0 = n - r0 * 28;
        sp0[nf] = r0 * 30 + q0;
        key0[nf] = q0 + 4 * r0;
    }

    // A: contiguous 4096B block per (wave,step); lane offset kcol*64B + klo*16B.
    const short* pA = (const short*)wrt + ((size_t)(kw2 * 36) * 4 + mw) * 2048 + kcol * 32 + klo * 8;

    f32x4 acc[4][7];
#pragma unroll
    for (int mf = 0; mf < 4; ++mf)
#pragma unroll
        for (int nf = 0; nf < 7; ++nf) acc[mf][nf] = (f32x4){0.f, 0.f, 0.f, 0.f};

    // preload steps 0 (E) and 1 (O)
    bf16x8 aE0 = *(const bf16x8*)(pA);
    bf16x8 aE1 = *(const bf16x8*)(pA + 512);
    bf16x8 aE2 = *(const bf16x8*)(pA + 1024);
    bf16x8 aE3 = *(const bf16x8*)(pA + 1536);
    pA += 8192;
    bf16x8 aO0 = *(const bf16x8*)(pA);
    bf16x8 aO1 = *(const bf16x8*)(pA + 512);
    bf16x8 aO2 = *(const bf16x8*)(pA + 1024);
    bf16x8 aO3 = *(const bf16x8*)(pA + 1536);
    pA += 8192;

    for (int tap = 0; tap < 9; ++tap) {
        const int kh = (tap * 11) >> 5;     // tap/3
        const int kwk = tap - kh * 3;
        unsigned tb[7];
#pragma unroll
        for (int nf = 0; nf < 7; ++nf) {
            int spv = sp0[nf] + kh * 30 + kwk;
            int key = (key0[nf] + kwk + 4 * kh) & 7;
            tb[nf] = (unsigned)(spv * 512) + (unsigned)(((klo ^ (key & 3)) << 4) | ((key >> 2) << 6));
        }
        STEP(aE0, aE1, aE2, aE3, 0)
        STEP(aO0, aO1, aO2, aO3, 1)
        STEP(aE0, aE1, aE2, aE3, 2)
        STEP(aO0, aO1, aO2, aO3, 3)
    }

    // ---- epilogue: combine k-halves through LDS (slab is dead), 2 rounds of 2 m-frags.
    __syncthreads();
    float* Xf = (float*)Xs;
#pragma unroll
    for (int r2 = 0; r2 < 2; ++r2) {
        if (kw2 == 1) {
#pragma unroll
            for (int mfi = 0; mfi < 2; ++mfi) {
                const int mf = r2 * 2 + mfi;
#pragma unroll
                for (int nf = 0; nf < 7; ++nf) {
#pragma unroll
                    for (int rr = 0; rr < 4; ++rr) {
                        int o = mw * 64 + mf * 16 + klo * 4 + rr;
                        int idx = (((mw * 2 + mfi) * 7 + nf) * 4 + rr) * 64 + lane;
                        Xf[idx] = hsm[2 * o + 1] * acc[mf][nf][rr];
                    }
                }
            }
        }
        __syncthreads();
        if (kw2 == 0) {
#pragma unroll
            for (int mfi = 0; mfi < 2; ++mfi) {
                const int mf = r2 * 2 + mfi;
#pragma unroll
                for (int nf = 0; nf < 7; ++nf) {
#pragma unroll
                    for (int rr = 0; rr < 4; ++rr) {
                        int o = mw * 64 + mf * 16 + klo * 4 + rr;
                        int idx = (((mw * 2 + mfi) * 7 + nf) * 4 + rr) * 64 + lane;
                        float y = hsm[2 * o] * acc[mf][nf][rr] + Xf[idx];
                        out[((size_t)b * NO + o) * 784 + nt * 112 + nf * 16 + kcol] = y;
                    }
                }
            }
        }
        __syncthreads();
    }
}

extern "C" void kernel_launch(void* const* d_in, const int* in_sizes, int n_in,
                              void* d_out, int out_size, void* d_ws, size_t ws_size,
                              hipStream_t stream) {
    const float* x = (const float*)d_in[0];
    const float* xg = (const float*)d_in[1];
    const float* w1 = (const float*)d_in[2];
    const float* b1 = (const float*)d_in[3];
    const float* w2 = (const float*)d_in[4];
    float* out = (float*)d_out;

    char* ws = (char*)d_ws;
    __hip_bfloat16* wrt = (__hip_bfloat16*)ws;                // 1,179,648 B
    __hip_bfloat16* xp = (__hip_bfloat16*)(ws + 1179648);     // 14,745,600 B (after wrt: prefetch overrun lands here harmlessly)

    wrt_kernel<<<288, 256, 0, stream>>>(w2, wrt);
    xpose_kernel<<<NB * 30 * 4, 256, 0, stream>>>(x, xp);
    conv_kernel<<<224, 512, 0, stream>>>(xp, wrt, xg, w1, b1, out);
}

// Round 7
// 52.633 us; speedup vs baseline: 7.5209x; 1.0179x over previous
//
#include <hip/hip_runtime.h>
#include <hip/hip_bf16.h>

typedef __attribute__((ext_vector_type(8))) short bf16x8;
typedef __attribute__((ext_vector_type(4))) float f32x4;

#define NB 32
#define NO 256
#define XS_BYTES (6 * 30 * 512)   // 92160 B x-slab (6 rows x 30 cols x 256ch bf16)

// wrT blocked layout: [kw2][tap][ic][mw][mf][kcol][klo][e8]
// -> per (wave,step) the 4 A-fragments are one contiguous 4096 B block;
//    flat step index s = tap*4+ic advances the block by a constant 16384 B.
__global__ void wrt_kernel(const float* __restrict__ w2, __hip_bfloat16* __restrict__ wrt) {
    int idx = blockIdx.x * 256 + threadIdx.x;   // [0, 73728) groups of 8
    int klo = idx & 3;
    int t1 = idx >> 2;
    int kcol = t1 & 15;
    int t2 = t1 >> 4;
    int mf = t2 & 3;
    int t3 = t2 >> 2;
    int mw = t3 & 3;
    int t4 = t3 >> 2;
    int ic = t4 & 3;
    int t5 = t4 >> 2;           // kw2*9 + tap
    int tap = t5 % 9;
    int kw2 = t5 / 9;
    int o = mw * 64 + mf * 16 + kcol;
    int ch = kw2 * 128 + ic * 32 + klo * 8;
    const float* s = w2 + (size_t)o * 2304 + (size_t)ch * 9 + tap;
    union { bf16x8 v; __hip_bfloat16 e[8]; } u;
#pragma unroll
    for (int e = 0; e < 8; ++e) u.e[e] = __float2bfloat16(s[e * 9]);
    *(bf16x8*)((short*)wrt + (size_t)idx * 8) = u.v;
}

// xp[b][pr][q][i] = bf16(x[b][i][pr-1][q-1]) interior; borders written as zero here.
__global__ void xpose_kernel(const float* __restrict__ x, __hip_bfloat16* __restrict__ xp) {
    __shared__ float tile[64][29];
    int blk = blockIdx.x;
    int icnk = blk & 3;
    int t = blk >> 2;
    int pr = t % 30;
    int b = t / 30;
    int i0 = icnk * 64;
    __hip_bfloat16* dst = xp + ((size_t)(b * 30 + pr) * 30) * 256 + i0;
    const bf16x8 z = (bf16x8){0, 0, 0, 0, 0, 0, 0, 0};
    if (pr == 0 || pr == 29) {
        for (int e = threadIdx.x; e < 30 * 8; e += 256) {
            int q = e >> 3, part = e & 7;
            *(bf16x8*)((short*)(dst + (size_t)q * 256) + part * 8) = z;
        }
        return;
    }
    int p = pr - 1;
    for (int e = threadIdx.x; e < 64 * 28; e += 256) {
        int ii = e / 28, q = e % 28;
        tile[ii][q] = x[((b * 256 + i0 + ii) * 28 + p) * 28 + q];
    }
    __syncthreads();
    for (int e = threadIdx.x; e < 28 * 64; e += 256) {
        int q = e >> 6, ii = e & 63;
        dst[(size_t)(q + 1) * 256 + ii] = __float2bfloat16(tile[ii][q]);
    }
    if (threadIdx.x < 16) {
        int col = (threadIdx.x >> 3) * 29, part = threadIdx.x & 7;
        *(bf16x8*)((short*)(dst + (size_t)col * 256) + part * 8) = z;
    }
}

#define MM(A_, B_, mf_, nf_) \
    acc[mf_][nf_] = __builtin_amdgcn_mfma_f32_16x16x32_bf16(A_, B_, acc[mf_][nf_], 0, 0, 0);

#define CLUSTER(A0, A1, A2, A3, B0, B1, B2, B3, B4, B5, B6)       \
    __builtin_amdgcn_s_setprio(1);                                \
    MM(A0, B0, 0, 0) MM(A1, B0, 1, 0) MM(A2, B0, 2, 0) MM(A3, B0, 3, 0) \
    MM(A0, B1, 0, 1) MM(A1, B1, 1, 1) MM(A2, B1, 2, 1) MM(A3, B1, 3, 1) \
    MM(A0, B2, 0, 2) MM(A1, B2, 1, 2) MM(A2, B2, 2, 2) MM(A3, B2, 3, 2) \
    MM(A0, B3, 0, 3) MM(A1, B3, 1, 3) MM(A2, B3, 2, 3) MM(A3, B3, 3, 3) \
    MM(A0, B4, 0, 4) MM(A1, B4, 1, 4) MM(A2, B4, 2, 4) MM(A3, B4, 3, 4) \
    MM(A0, B5, 0, 5) MM(A1, B5, 1, 5) MM(A2, B5, 2, 5) MM(A3, B5, 3, 5) \
    MM(A0, B6, 0, 6) MM(A1, B6, 1, 6) MM(A2, B6, 2, 6) MM(A3, B6, 3, 6) \
    __builtin_amdgcn_s_setprio(0);

// B-fragment load: logical addr = u[nf] ^ ((k[nf]&7)<<4) ^ xo  (swizzle algebra
// identical to r5/r6's verified tb form; u carries spv*512 + klo*16).
#define LOADB(D0, D1, D2, D3, D4, D5, D6, XO)                                  \
    D0 = *(const bf16x8*)(Xs + ((u[0] ^ ((kk[0] & 7u) << 4)) ^ (XO)));         \
    D1 = *(const bf16x8*)(Xs + ((u[1] ^ ((kk[1] & 7u) << 4)) ^ (XO)));         \
    D2 = *(const bf16x8*)(Xs + ((u[2] ^ ((kk[2] & 7u) << 4)) ^ (XO)));         \
    D3 = *(const bf16x8*)(Xs + ((u[3] ^ ((kk[3] & 7u) << 4)) ^ (XO)));         \
    D4 = *(const bf16x8*)(Xs + ((u[4] ^ ((kk[4] & 7u) << 4)) ^ (XO)));         \
    D5 = *(const bf16x8*)(Xs + ((u[5] ^ ((kk[5] & 7u) << 4)) ^ (XO)));         \
    D6 = *(const bf16x8*)(Xs + ((u[6] ^ ((kk[6] & 7u) << 4)) ^ (XO)));

#define PFA(P0, P1, P2, P3)                   \
    P0 = *(const bf16x8*)(pA);                \
    P1 = *(const bf16x8*)(pA + 512);          \
    P2 = *(const bf16x8*)(pA + 1024);         \
    P3 = *(const bf16x8*)(pA + 1536);         \
    pA += 8192;

// even step: consume (aE, bc); prefetch A(s+2) into aE, B(s+1) into bn
#define STEPE(XON)                                          \
    {                                                       \
        bf16x8 q0, q1, q2, q3;                              \
        PFA(q0, q1, q2, q3)                                 \
        LOADB(bn0, bn1, bn2, bn3, bn4, bn5, bn6, XON)       \
        CLUSTER(aE0, aE1, aE2, aE3, bc0, bc1, bc2, bc3, bc4, bc5, bc6) \
        aE0 = q0; aE1 = q1; aE2 = q2; aE3 = q3;             \
    }
// odd step: consume (aO, bn); prefetch into aO / bc
#define STEPO(XON)                                          \
    {                                                       \
        bf16x8 q0, q1, q2, q3;                              \
        PFA(q0, q1, q2, q3)                                 \
        LOADB(bc0, bc1, bc2, bc3, bc4, bc5, bc6, XON)       \
        CLUSTER(aO0, aO1, aO2, aO3, bn0, bn1, bn2, bn3, bn4, bn5, bn6) \
        aO0 = q0; aO1 = q1; aO2 = q2; aO3 = q3;             \
    }

// Implicit-GEMM conv. 224 blocks (XCD-swizzled), 512 thr = 8 waves = 4 mw x 2 kw2.
// Wave (mw,kw2): 64 o (4 m-frags) x 112 n (7 n-frags) x its 128-ch half.
// Zero barriers in K-loop; A depth-2 global ring; B depth-1 LDS->reg ping-pong.
__global__ __launch_bounds__(512, 2) void conv_kernel(
    const __hip_bfloat16* __restrict__ xp, const __hip_bfloat16* __restrict__ wrt,
    const float* __restrict__ xg, const float* __restrict__ w1,
    const float* __restrict__ b1, float* __restrict__ out) {
    __shared__ __align__(16) char Xs[XS_BYTES];
    __shared__ float hsm[512];
    const int bid = blockIdx.x;
    const int v = (bid & 7) * 28 + (bid >> 3);   // bijective XCD swizzle (224 % 8 == 0)
    const int b = v / 7;
    const int nt = v - b * 7;
    const int tid = threadIdx.x;
    const int lane = tid & 63;
    const int wv = tid >> 6;
    const int mw = wv & 3;
    const int kw2 = wv >> 2;
    const int kcol = lane & 15;
    const int klo = lane >> 4;

    // h[j] = sigmoid(xg[b].w1[j] + b1[j])
    {
        float s = b1[tid];
        const float* g = xg + b * 16;
        const float* w = w1 + tid * 16;
#pragma unroll
        for (int c = 0; c < 16; ++c) s += g[c] * w[c];
        hsm[tid] = 1.0f / (1.0f + expf(-s));
    }

    // stage slab: linear coalesced global read; 16B chunk w of position sp stored at
    // sp*512 + ((w ^ key(sp))<<4), key(sp) = (q + 4r)&7 (conflict-free, 4*30 == 0 mod 8).
    {
        const char* src = (const char*)(xp + ((size_t)b * 900 + nt * 120) * 256);
        for (int c = tid; c < 5760; c += 512) {
            int sp = c >> 5, w = c & 31;
            int rr = sp / 30;
            int qq = sp - rr * 30;
            int key = (qq + 4 * rr) & 7;
            *(bf16x8*)(Xs + sp * 512 + ((w ^ key) << 4)) = *(const bf16x8*)(src + (size_t)c * 16);
        }
    }
    __syncthreads();

    // per-lane B geometry, incremental per-tap: u += dspv*512, kk += dkey
    unsigned u[7], kk[7];
#pragma unroll
    for (int nf = 0; nf < 7; ++nf) {
        int n = nf * 16 + kcol;
        int r0 = n / 28;
        int q0 = n - r0 * 28;
        u[nf] = (unsigned)((r0 * 30 + q0) * 512 + (klo << 4));
        kk[nf] = (unsigned)(q0 + 4 * r0);
    }
    const unsigned xo0 = (unsigned)((kw2 * 4 + 0) << 6);
    const unsigned xo1 = (unsigned)((kw2 * 4 + 1) << 6);
    const unsigned xo2 = (unsigned)((kw2 * 4 + 2) << 6);
    const unsigned xo3 = (unsigned)((kw2 * 4 + 3) << 6);

    // A: contiguous 4096B block per (wave,step); lane offset kcol*64B + klo*16B.
    const short* pA = (const short*)wrt + ((size_t)(kw2 * 36) * 4 + mw) * 2048 + kcol * 32 + klo * 8;

    f32x4 acc[4][7];
#pragma unroll
    for (int mf = 0; mf < 4; ++mf)
#pragma unroll
        for (int nf = 0; nf < 7; ++nf) acc[mf][nf] = (f32x4){0.f, 0.f, 0.f, 0.f};

    bf16x8 aE0, aE1, aE2, aE3, aO0, aO1, aO2, aO3;
    bf16x8 bc0, bc1, bc2, bc3, bc4, bc5, bc6;
    bf16x8 bn0, bn1, bn2, bn3, bn4, bn5, bn6;

    PFA(aE0, aE1, aE2, aE3)               // step 0
    PFA(aO0, aO1, aO2, aO3)               // step 1
    LOADB(bc0, bc1, bc2, bc3, bc4, bc5, bc6, xo0)   // B(tap0, ic0)

    for (int tap = 0; tap < 9; ++tap) {
        STEPE(xo1)                        // ic0: pf B(ic1)
        STEPO(xo2)                        // ic1: pf B(ic2)
        STEPE(xo3)                        // ic2: pf B(ic3)
        if (tap < 8) {                    // advance geometry to tap+1 before ic3's prefetch
            const int cross = (tap == 2 || tap == 5);
            const unsigned da = cross ? 28u * 512u : 512u;
            const unsigned dk = cross ? 2u : 1u;
#pragma unroll
            for (int nf = 0; nf < 7; ++nf) { u[nf] += da; kk[nf] += dk; }
        }
        STEPO(xo0)                        // ic3: pf B(tap+1, ic0) (tap8: dead reload)
    }

    // ---- epilogue: combine k-halves through LDS (slab is dead), 2 rounds of 2 m-frags.
    __syncthreads();
    float* Xf = (float*)Xs;
#pragma unroll
    for (int r2 = 0; r2 < 2; ++r2) {
        if (kw2 == 1) {
#pragma unroll
            for (int mfi = 0; mfi < 2; ++mfi) {
                const int mf = r2 * 2 + mfi;
#pragma unroll
                for (int nf = 0; nf < 7; ++nf) {
#pragma unroll
                    for (int rr = 0; rr < 4; ++rr) {
                        int o = mw * 64 + mf * 16 + klo * 4 + rr;
                        int idx = (((mw * 2 + mfi) * 7 + nf) * 4 + rr) * 64 + lane;
                        Xf[idx] = hsm[2 * o + 1] * acc[mf][nf][rr];
                    }
                }
            }
        }
        __syncthreads();
        if (kw2 == 0) {
#pragma unroll
            for (int mfi = 0; mfi < 2; ++mfi) {
                const int mf = r2 * 2 + mfi;
#pragma unroll
                for (int nf = 0; nf < 7; ++nf) {
#pragma unroll
                    for (int rr = 0; rr < 4; ++rr) {
                        int o = mw * 64 + mf * 16 + klo * 4 + rr;
                        int idx = (((mw * 2 + mfi) * 7 + nf) * 4 + rr) * 64 + lane;
                        float y = hsm[2 * o] * acc[mf][nf][rr] + Xf[idx];
                        out[((size_t)b * NO + o) * 784 + nt * 112 + nf * 16 + kcol] = y;
                    }
                }
            }
        }
        __syncthreads();
    }
}

extern "C" void kernel_launch(void* const* d_in, const int* in_sizes, int n_in,
                              void* d_out, int out_size, void* d_ws, size_t ws_size,
                              hipStream_t stream) {
    const float* x = (const float*)d_in[0];
    const float* xg = (const float*)d_in[1];
    const float* w1 = (const float*)d_in[2];
    const float* b1 = (const float*)d_in[3];
    const float* w2 = (const float*)d_in[4];
    float* out = (float*)d_out;

    char* ws = (char*)d_ws;
    __hip_bfloat16* wrt = (__hip_bfloat16*)ws;                // 1,179,648 B
    __hip_bfloat16* xp = (__hip_bfloat16*)(ws + 1179648);     // 14,745,600 B (A-ring overrun lands here harmlessly)

    wrt_kernel<<<288, 256, 0, stream>>>(w2, wrt);
    xpose_kernel<<<NB * 30 * 4, 256, 0, stream>>>(x, xp);
    conv_kernel<<<224, 512, 0, stream>>>(xp, wrt, xg, w1, b1, out);
}

// Round 8
// 50.385 us; speedup vs baseline: 7.8564x; 1.0446x over previous
//
#include <hip/hip_runtime.h>
#include <hip/hip_bf16.h>

typedef __attribute__((ext_vector_type(8))) short bf16x8;
typedef __attribute__((ext_vector_type(4))) float f32x4;

#define NB 32
#define NO 256
#define XS_BYTES (6 * 30 * 512)   // 92160 B x-slab (6 rows x 30 cols x 256ch bf16)

static __device__ __forceinline__ void gld16(const void* g, void* l) {
    __builtin_amdgcn_global_load_lds(
        (const __attribute__((address_space(1))) void*)g,
        (__attribute__((address_space(3))) void*)l, 16, 0, 0);
}

// Fused prep: blocks [0,288) build wrt; blocks [288, 288+3840) build xp.
// wrt layout, groups of 8 shorts: [s=tap*4+ic][kw2][mw][mf][klo][kcol][e8]
// -> per (step, wave=kw2*4+mw) one contiguous 4096B block, lane-linear (lane=klo*16+kcol).
__global__ void prep_kernel(const float* __restrict__ w2, __hip_bfloat16* __restrict__ wrt,
                            const float* __restrict__ x, __hip_bfloat16* __restrict__ xp) {
    if (blockIdx.x < 288) {
        int idx = blockIdx.x * 256 + threadIdx.x;   // group id in [0, 73728)
        int kcol = idx & 15;
        int klo = (idx >> 4) & 3;
        int mf = (idx >> 6) & 3;
        int mw = (idx >> 8) & 3;
        int kw2 = (idx >> 10) & 1;
        int s = idx >> 11;            // 0..35
        int tap = s >> 2;
        int ic = s & 3;
        int o = mw * 64 + mf * 16 + kcol;
        int ch = kw2 * 128 + ic * 32 + klo * 8;
        const float* src = w2 + (size_t)o * 2304 + (size_t)ch * 9 + tap;
        union { bf16x8 v; __hip_bfloat16 e[8]; } u;
#pragma unroll
        for (int e = 0; e < 8; ++e) u.e[e] = __float2bfloat16(src[e * 9]);
        *(bf16x8*)((short*)wrt + (size_t)idx * 8) = u.v;
        return;
    }
    // xpose: xp[b][pr][q][i] = bf16(x[b][i][pr-1][q-1]) interior; borders zeroed here.
    __shared__ float tile[64][29];
    int blk = blockIdx.x - 288;
    int icnk = blk & 3;
    int t = blk >> 2;
    int pr = t % 30;
    int b = t / 30;
    int i0 = icnk * 64;
    __hip_bfloat16* dst = xp + ((size_t)(b * 30 + pr) * 30) * 256 + i0;
    const bf16x8 z = (bf16x8){0, 0, 0, 0, 0, 0, 0, 0};
    if (pr == 0 || pr == 29) {
        for (int e = threadIdx.x; e < 30 * 8; e += 256) {
            int q = e >> 3, part = e & 7;
            *(bf16x8*)((short*)(dst + (size_t)q * 256) + part * 8) = z;
        }
        return;
    }
    int p = pr - 1;
    for (int e = threadIdx.x; e < 64 * 28; e += 256) {
        int ii = e / 28, q = e % 28;
        tile[ii][q] = x[((b * 256 + i0 + ii) * 28 + p) * 28 + q];
    }
    __syncthreads();
    for (int e = threadIdx.x; e < 28 * 64; e += 256) {
        int q = e >> 6, ii = e & 63;
        dst[(size_t)(q + 1) * 256 + ii] = __float2bfloat16(tile[ii][q]);
    }
    if (threadIdx.x < 16) {
        int col = (threadIdx.x >> 3) * 29, part = threadIdx.x & 7;
        *(bf16x8*)((short*)(dst + (size_t)col * 256) + part * 8) = z;
    }
}

#define MM(A_, B_, mf_, nf_) \
    acc[mf_][nf_] = __builtin_amdgcn_mfma_f32_16x16x32_bf16(A_, B_, acc[mf_][nf_], 0, 0, 0);

#define CLUSTER(A0, A1, A2, A3, B0, B1, B2, B3, B4, B5, B6)             \
    __builtin_amdgcn_s_setprio(1);                                      \
    MM(A0, B0, 0, 0) MM(A1, B0, 1, 0) MM(A2, B0, 2, 0) MM(A3, B0, 3, 0) \
    MM(A0, B1, 0, 1) MM(A1, B1, 1, 1) MM(A2, B1, 2, 1) MM(A3, B1, 3, 1) \
    MM(A0, B2, 0, 2) MM(A1, B2, 1, 2) MM(A2, B2, 2, 2) MM(A3, B2, 3, 2) \
    MM(A0, B3, 0, 3) MM(A1, B3, 1, 3) MM(A2, B3, 2, 3) MM(A3, B3, 3, 3) \
    MM(A0, B4, 0, 4) MM(A1, B4, 1, 4) MM(A2, B4, 2, 4) MM(A3, B4, 3, 4) \
    MM(A0, B5, 0, 5) MM(A1, B5, 1, 5) MM(A2, B5, 2, 5) MM(A3, B5, 3, 5) \
    MM(A0, B6, 0, 6) MM(A1, B6, 1, 6) MM(A2, B6, 2, 6) MM(A3, B6, 3, 6) \
    __builtin_amdgcn_s_setprio(0);

#define LOADB(D0, D1, D2, D3, D4, D5, D6, XO)                                  \
    D0 = *(const bf16x8*)(Xs + ((u[0] ^ ((kk[0] & 7u) << 4)) ^ (XO)));         \
    D1 = *(const bf16x8*)(Xs + ((u[1] ^ ((kk[1] & 7u) << 4)) ^ (XO)));         \
    D2 = *(const bf16x8*)(Xs + ((u[2] ^ ((kk[2] & 7u) << 4)) ^ (XO)));         \
    D3 = *(const bf16x8*)(Xs + ((u[3] ^ ((kk[3] & 7u) << 4)) ^ (XO)));         \
    D4 = *(const bf16x8*)(Xs + ((u[4] ^ ((kk[4] & 7u) << 4)) ^ (XO)));         \
    D5 = *(const bf16x8*)(Xs + ((u[5] ^ ((kk[5] & 7u) << 4)) ^ (XO)));         \
    D6 = *(const bf16x8*)(Xs + ((u[6] ^ ((kk[6] & 7u) << 4)) ^ (XO)));

// One K-step (step s = tap*4 + ICV, buffer parity = ICV&1):
//  - DMA-stage step s+1 into this wave's other buffer (skip at the last step)
//  - load 7 B-frags from Xs (swizzled)
//  - counted vmcnt(4): stage(s) landed, stage(s+1) still in flight (never drain mid-loop)
//  - 4 A-frag ds_read_b128 (lane-linear, conflict-free) + 28-MFMA setprio cluster
#define PHASE(ICV, XOv)                                                        \
    {                                                                          \
        if ((ICV) != 3 || tap < 8) {                                           \
            char* l = AbW + ((((ICV) + 1) & 1) * 4096);                        \
            gld16(pG, l);                                                      \
            gld16(pG + 1024, l + 1024);                                        \
            gld16(pG + 2048, l + 2048);                                        \
            gld16(pG + 3072, l + 3072);                                        \
            pG += 32768;                                                       \
        }                                                                      \
        bf16x8 bv0, bv1, bv2, bv3, bv4, bv5, bv6;                              \
        LOADB(bv0, bv1, bv2, bv3, bv4, bv5, bv6, XOv)                          \
        if ((ICV) == 3 && tap == 8) {                                          \
            asm volatile("s_waitcnt vmcnt(0)" ::: "memory");                   \
        } else {                                                               \
            asm volatile("s_waitcnt vmcnt(4)" ::: "memory");                   \
        }                                                                      \
        const char* ar = AbR + (((ICV) & 1) * 4096);                           \
        bf16x8 a0 = *(const bf16x8*)(ar);                                      \
        bf16x8 a1 = *(const bf16x8*)(ar + 1024);                               \
        bf16x8 a2 = *(const bf16x8*)(ar + 2048);                               \
        bf16x8 a3 = *(const bf16x8*)(ar + 3072);                               \
        CLUSTER(a0, a1, a2, a3, bv0, bv1, bv2, bv3, bv4, bv5, bv6)             \
    }

// Implicit-GEMM conv. 224 blocks (XCD-swizzled), 512 thr = 8 waves = (kw2*4+mw).
// Wave: 64 o x 112 n x its 128-ch half. Zero barriers in K-loop; A via per-wave
// global_load_lds double-buffer ring with counted vmcnt.
__global__ __launch_bounds__(512, 2) void conv_kernel(
    const __hip_bfloat16* __restrict__ xp, const __hip_bfloat16* __restrict__ wrt,
    const float* __restrict__ xg, const float* __restrict__ w1,
    const float* __restrict__ b1, float* __restrict__ out) {
    __shared__ __align__(16) char Xs[XS_BYTES];      // 92160
    __shared__ __align__(16) char Ab[8 * 2 * 4096];  // 65536
    __shared__ float hsm[512];                       // 2048  -> 159744 total
    const int bid = blockIdx.x;
    const int v = (bid & 7) * 28 + (bid >> 3);   // bijective XCD swizzle (224 % 8 == 0)
    const int b = v / 7;
    const int nt = v - b * 7;
    const int tid = threadIdx.x;
    const int lane = tid & 63;
    const int wv = tid >> 6;
    const int mw = wv & 3;
    const int kw2 = wv >> 2;
    const int kcol = lane & 15;
    const int klo = lane >> 4;

    const char* wrtc = (const char*)wrt;
    char* AbW = Ab + wv * 8192;                  // wave-uniform DMA dest base
    const char* AbR = Ab + wv * 8192 + lane * 16;
    const char* pG0 = wrtc + wv * 4096 + lane * 16;

    // stage step 0 into buf0 (drained by the prologue __syncthreads)
    gld16(pG0, AbW);
    gld16(pG0 + 1024, AbW + 1024);
    gld16(pG0 + 2048, AbW + 2048);
    gld16(pG0 + 3072, AbW + 3072);
    const char* pG = pG0 + 32768;                // next staged step = 1

    // h[j] = sigmoid(xg[b].w1[j] + b1[j])
    {
        float s = b1[tid];
        const float* g = xg + b * 16;
        const float* w = w1 + tid * 16;
#pragma unroll
        for (int c = 0; c < 16; ++c) s += g[c] * w[c];
        hsm[tid] = 1.0f / (1.0f + expf(-s));
    }

    // stage x-slab: linear coalesced global read; 16B chunk w of position sp stored at
    // sp*512 + ((w ^ key(sp))<<4), key(sp) = (q + 4r)&7 (conflict-free, 4*30 == 0 mod 8).
    {
        const char* src = (const char*)(xp + ((size_t)b * 900 + nt * 120) * 256);
        for (int c = tid; c < 5760; c += 512) {
            int sp = c >> 5, w = c & 31;
            int rr = sp / 30;
            int qq = sp - rr * 30;
            int key = (qq + 4 * rr) & 7;
            *(bf16x8*)(Xs + sp * 512 + ((w ^ key) << 4)) = *(const bf16x8*)(src + (size_t)c * 16);
        }
    }
    __syncthreads();   // drains vmcnt(0) + lgkmcnt(0): step-0 DMA and Xs both ready

    // per-lane B geometry, incremental per-tap: u += dspv*512, kk += dkey
    unsigned u[7], kk[7];
#pragma unroll
    for (int nf = 0; nf < 7; ++nf) {
        int n = nf * 16 + kcol;
        int r0 = n / 28;
        int q0 = n - r0 * 28;
        u[nf] = (unsigned)((r0 * 30 + q0) * 512 + (klo << 4));
        kk[nf] = (unsigned)(q0 + 4 * r0);
    }
    const unsigned xo0 = (unsigned)((kw2 * 4 + 0) << 6);
    const unsigned xo1 = (unsigned)((kw2 * 4 + 1) << 6);
    const unsigned xo2 = (unsigned)((kw2 * 4 + 2) << 6);
    const unsigned xo3 = (unsigned)((kw2 * 4 + 3) << 6);

    f32x4 acc[4][7];
#pragma unroll
    for (int mf = 0; mf < 4; ++mf)
#pragma unroll
        for (int nf = 0; nf < 7; ++nf) acc[mf][nf] = (f32x4){0.f, 0.f, 0.f, 0.f};

    for (int tap = 0; tap < 9; ++tap) {
        PHASE(0, xo0)
        PHASE(1, xo1)
        PHASE(2, xo2)
        PHASE(3, xo3)
        if (tap < 8) {
            const int cross = (tap == 2 || tap == 5);
            const unsigned da = cross ? 28u * 512u : 512u;
            const unsigned dk = cross ? 2u : 1u;
#pragma unroll
            for (int nf = 0; nf < 7; ++nf) { u[nf] += da; kk[nf] += dk; }
        }
    }

    // ---- epilogue: combine k-halves through LDS (Xs is dead), 2 rounds of 2 m-frags.
    __syncthreads();
    float* Xf = (float*)Xs;
#pragma unroll
    for (int r2 = 0; r2 < 2; ++r2) {
        if (kw2 == 1) {
#pragma unroll
            for (int mfi = 0; mfi < 2; ++mfi) {
                const int mf = r2 * 2 + mfi;
#pragma unroll
                for (int nf = 0; nf < 7; ++nf) {
#pragma unroll
                    for (int rr = 0; rr < 4; ++rr) {
                        int o = mw * 64 + mf * 16 + klo * 4 + rr;
                        int idx = (((mw * 2 + mfi) * 7 + nf) * 4 + rr) * 64 + lane;
                        Xf[idx] = hsm[2 * o + 1] * acc[mf][nf][rr];
                    }
                }
            }
        }
        __syncthreads();
        if (kw2 == 0) {
#pragma unroll
            for (int mfi = 0; mfi < 2; ++mfi) {
                const int mf = r2 * 2 + mfi;
#pragma unroll
                for (int nf = 0; nf < 7; ++nf) {
#pragma unroll
                    for (int rr = 0; rr < 4; ++rr) {
                        int o = mw * 64 + mf * 16 + klo * 4 + rr;
                        int idx = (((mw * 2 + mfi) * 7 + nf) * 4 + rr) * 64 + lane;
                        float y = hsm[2 * o] * acc[mf][nf][rr] + Xf[idx];
                        out[((size_t)b * NO + o) * 784 + nt * 112 + nf * 16 + kcol] = y;
                    }
                }
            }
        }
        __syncthreads();
    }
}

extern "C" void kernel_launch(void* const* d_in, const int* in_sizes, int n_in,
                              void* d_out, int out_size, void* d_ws, size_t ws_size,
                              hipStream_t stream) {
    const float* x = (const float*)d_in[0];
    const float* xg = (const float*)d_in[1];
    const float* w1 = (const float*)d_in[2];
    const float* b1 = (const float*)d_in[3];
    const float* w2 = (const float*)d_in[4];
    float* out = (float*)d_out;

    char* ws = (char*)d_ws;
    __hip_bfloat16* wrt = (__hip_bfloat16*)ws;                // 1,179,648 B
    __hip_bfloat16* xp = (__hip_bfloat16*)(ws + 1179648);     // 14,745,600 B

    prep_kernel<<<288 + NB * 30 * 4, 256, 0, stream>>>(w2, wrt, x, xp);
    conv_kernel<<<224, 512, 0, stream>>>(xp, wrt, xg, w1, b1, out);
}